// Round 9
// baseline (3607.782 us; speedup 1.0000x reference)
//
#include <hip/hip_runtime.h>

// Round 17: R16 with the rec_l3 launch-size bug fixed (was launched with the
// old 4-lane 128 threads; the 8-lane body needs 240 -> 256. Units 16-29 of
// the LAST layer were never computed -> absmax 6.4e-2).
// 8-lanes-per-unit recurrence (serial R0 chunk structure, TC=128):
//  - 8 lanes/unit halves per-lane weights (32 packed f16x2 regs for l0) ->
//    truly VGPR-resident, and halves per-lane dot work (32 fdot2/step).
//  - Butterfly: dpp 0xB1, 0x4E, + 0x141 row_half_mirror (each 8-lane group
//    is exactly a half-row). All 8 lanes get all 4 gate sums; quad dpp_mov
//    gather unchanged. Activation distributed by g = lane&3.
//  - Precision path (f16 h in LDS + f16 weights + fdot2 f32-acc) measured
//    in R15: absmax 2.4e-4 vs 1.357e-3 threshold.

#define BATCH 256
#define TFULL 1024
#define TC    128
#define NCHUNK (TFULL / TC)

typedef __attribute__((ext_vector_type(2))) _Float16 f16x2;
typedef __attribute__((ext_vector_type(4))) _Float16 f16x4;

__device__ __forceinline__ float fast_rcp(float x) {
    return __builtin_amdgcn_rcpf(x);
}

__device__ __forceinline__ float tanh_fast(float x) {
    float e = __expf(-2.0f * fabsf(x));
    float r = fast_rcp(1.0f + e);
    return copysignf(fmaf(2.0f, r, -1.0f), x);
}

__device__ __forceinline__ float fdot2_(f16x2 a, f16x2 b, float c) {
#if __has_builtin(__builtin_amdgcn_fdot2)
    return __builtin_amdgcn_fdot2(a, b, c, false);
#else
    float d;
    asm("v_dot2_f32_f16 %0, %1, %2, %3" : "=v"(d) : "v"(a), "v"(b), "v"(c));
    return d;
#endif
}

// LDS-only barrier: does NOT drain vmcnt (global loads/stores stay in
// flight). Safe: the rec loop's barrier only orders the LDS h handoff.
__device__ __forceinline__ void lds_barrier() {
    asm volatile("s_waitcnt lgkmcnt(0)\n\ts_barrier" ::: "memory");
}

template<int CTRL>
__device__ __forceinline__ float dpp_add(float v) {
    int t = __builtin_amdgcn_update_dpp(0, __float_as_int(v), CTRL, 0xF, 0xF, true);
    return v + __int_as_float(t);
}
template<int CTRL>
__device__ __forceinline__ float dpp_mov(float v) {
    int t = __builtin_amdgcn_update_dpp(0, __float_as_int(v), CTRL, 0xF, 0xF, true);
    return __int_as_float(t);
}

// ---------------- Phase A: xg = x @ Wx + bias (R0 baseline, verbatim) -----
template<int K, int N>
__global__ __launch_bounds__(256, 2)
void xg_gemm(const float* __restrict__ x, int batchStride,
             const float* __restrict__ Wx,    // [K, N]
             const float* __restrict__ bias,  // [N]
             float* __restrict__ out)
{
    constexpr int K4   = (K + 3) / 4;
    constexpr int SLAB = 64 * 4 + 4;

    const int n0   = blockIdx.x * 64;
    const int row0 = blockIdx.y * 64;
    const int tid  = threadIdx.x;
    const int tx   = tid & 15;
    const int ty   = tid >> 4;

    __shared__ __align__(16) float s_A[K4 * SLAB];
    __shared__ __align__(16) float s_B[K4 * 4 * 64];

    if constexpr ((K % 4) == 0) {
        for (int i = tid; i < 64 * (K / 4); i += 256) {
            const int row = i / (K / 4);
            const int k4  = i % (K / 4);
            const int gr  = row0 + row;
            const int b   = gr >> 7;
            const int t   = gr & 127;
            float4 v = *(const float4*)(x + (size_t)b * batchStride + t * K + k4 * 4);
            *(float4*)(s_A + k4 * SLAB + row * 4) = v;
        }
    } else {
        for (int i = tid; i < 64 * K; i += 256) {
            const int row = i / K;
            const int k   = i % K;
            const int gr  = row0 + row;
            const int b   = gr >> 7;
            const int t   = gr & 127;
            s_A[(k >> 2) * SLAB + row * 4 + (k & 3)] =
                x[(size_t)b * batchStride + t * K + k];
        }
        constexpr int PAD = K4 * 4 - K;
        for (int i = tid; i < 64 * PAD; i += 256) {
            const int row = i / PAD;
            const int kk  = K + i % PAD;
            s_A[(kk >> 2) * SLAB + row * 4 + (kk & 3)] = 0.0f;
        }
    }

    for (int i = tid; i < K4 * 4 * 16; i += 256) {
        const int k  = i >> 4;
        const int c4 = i & 15;
        float4 v = {0.0f, 0.0f, 0.0f, 0.0f};
        if (k < K && n0 + c4 * 4 < N)
            v = *(const float4*)(Wx + (size_t)k * N + n0 + c4 * 4);
        *(float4*)(s_B + k * 64 + c4 * 4) = v;
    }
    __syncthreads();

    float acc[4][4];
#pragma unroll
    for (int r = 0; r < 4; ++r)
#pragma unroll
        for (int c = 0; c < 4; ++c) acc[r][c] = 0.0f;

    for (int k4 = 0; k4 < K4; ++k4) {
        float4 bv[4];
#pragma unroll
        for (int j = 0; j < 4; ++j)
            bv[j] = *(const float4*)(s_B + (k4 * 4 + j) * 64 + tx * 4);
#pragma unroll
        for (int r = 0; r < 4; ++r) {
            float4 av = *(const float4*)(s_A + k4 * SLAB + (ty + 16 * r) * 4);
#pragma unroll
            for (int c = 0; c < 4; ++c) {
                acc[r][c] = fmaf(av.x, ((const float*)&bv[0])[c], acc[r][c]);
                acc[r][c] = fmaf(av.y, ((const float*)&bv[1])[c], acc[r][c]);
                acc[r][c] = fmaf(av.z, ((const float*)&bv[2])[c], acc[r][c]);
                acc[r][c] = fmaf(av.w, ((const float*)&bv[3])[c], acc[r][c]);
            }
        }
    }

    if (n0 + tx * 4 < N) {
        float4 bb = *(const float4*)(bias + n0 + tx * 4);
#pragma unroll
        for (int r = 0; r < 4; ++r) {
            float4 o;
            o.x = acc[r][0] + bb.x;
            o.y = acc[r][1] + bb.y;
            o.z = acc[r][2] + bb.z;
            o.w = acc[r][3] + bb.w;
            *(float4*)(out + (size_t)(row0 + ty + 16 * r) * N + n0 + tx * 4) = o;
        }
    }
}

// ---------------- Phase B: recurrence, 8 lanes/unit ----------------------
// Lane (u = tid>>3, s = tid&7): k-slice [s*S, s*S+S), S mult of 4.
// Each lane accumulates all 4 gate partials over its slice (packed f16
// fdot2); 3-stage dpp butterfly (0xB1, 0x4E, 0x141=row_half_mirror) sums
// over the 8-lane group (= one half-row). Lane finalizes gate g = s&3
// (pairs s, s+4 redundant); quad dpp_mov gather; replicated c/h update.
template<int U, int S, int BLOCK, bool LAST>
__device__ __forceinline__ void rec8_body(
    _Float16* __restrict__ s_h,     // [2][8*S] f16 in LDS
    const float* __restrict__ xg,   // [B, TC, G]
    const float* __restrict__ Wh,   // [U, G]
    float* __restrict__ xout,       // [B, TC, U] (unless LAST)
    float* __restrict__ c_state,    // [B*U]
    float* __restrict__ h_state,    // [B*U]
    int first,
    const float* __restrict__ Wout, // [U] (LAST)
    const float* __restrict__ bout, // [1] (LAST)
    float* __restrict__ dout)       // [B] (LAST)
{
    constexpr int G  = 4 * U;
    constexpr int HS = 8 * S;

    const int b   = blockIdx.x;
    const int tid = threadIdx.x;
    const int u   = tid >> 3;
    const int s   = tid & 7;
    const int g   = s & 3;
    const bool act_th = (u < U);
    const int uu  = act_th ? u : 0;
    const bool wave_act = ((tid & ~63) < 8 * U);

    // packed f16 weight pairs: w[gate][p] = (Wh[k0][gate*U+u], Wh[k1][..])
    // k0 = s*S + 2p
    f16x2 w[4][S / 2];
#pragma unroll
    for (int gg = 0; gg < 4; ++gg)
#pragma unroll
        for (int p = 0; p < S / 2; ++p) {
            const int k0 = s * S + 2 * p;
            const int k1 = k0 + 1;
            const float wa = (act_th && k0 < U) ? Wh[(size_t)k0 * G + gg * U + uu] : 0.0f;
            const float wb = (act_th && k1 < U) ? Wh[(size_t)k1 * G + gg * U + uu] : 0.0f;
            w[gg][p] = (f16x2){(_Float16)wa, (_Float16)wb};
        }

    for (int i = tid; i < 2 * HS; i += BLOCK) s_h[i] = (_Float16)0.0f;
    __syncthreads();
    if (tid < U) s_h[tid] = (_Float16)(first ? 0.0f : h_state[b * U + tid]);
    float c = first ? 0.0f : c_state[b * U + uu];
    __syncthreads();

    const float* xgp = xg + (size_t)b * TC * G + (g * U + uu);
    float xg0 = xgp[0];
    float xg1 = xgp[G];

    int cur = 0;
    float h = 0.0f, hprev = 0.0f;
    const bool is_t = (g == 2);

    for (int t = 0; t < TC; ++t, cur ^= 1) {
        if (wave_act) {
            // (1) t+2 prefetch: waited at USE two steps from now
            const int tp = (t + 2 < TC) ? (t + 2) : (TC - 1);
            const float xg2 = xgp[(size_t)tp * G];

            // (2) deferred global store of last step's h
            if (!LAST) {
                if (act_th && s == 0 && t > 0)
                    xout[((size_t)b * TC + (t - 1)) * U + u] = hprev;
            }

            // (3) partial dots over this lane's k-slice, all 4 gates
            float a0 = 0.0f, a1 = 0.0f, a2 = 0.0f, a3 = 0.0f;
            const _Float16* hs = s_h + cur * HS + s * S;
#pragma unroll
            for (int kk = 0; kk < S; kk += 4) {
                f16x4 v = *(const f16x4*)(hs + kk);
                f16x2 lo = __builtin_shufflevector(v, v, 0, 1);
                f16x2 hi = __builtin_shufflevector(v, v, 2, 3);
                const int p = kk >> 1;
                a0 = fdot2_(lo, w[0][p],     a0);
                a0 = fdot2_(hi, w[0][p + 1], a0);
                a1 = fdot2_(lo, w[1][p],     a1);
                a1 = fdot2_(hi, w[1][p + 1], a1);
                a2 = fdot2_(lo, w[2][p],     a2);
                a2 = fdot2_(hi, w[2][p + 1], a2);
                a3 = fdot2_(lo, w[3][p],     a3);
                a3 = fdot2_(hi, w[3][p + 1], a3);
            }

            // (4) 8-lane butterfly: pair, quad, cross-quad (half-row mirror)
            a0 = dpp_add<0xB1>(a0); a0 = dpp_add<0x4E>(a0); a0 = dpp_add<0x141>(a0);
            a1 = dpp_add<0xB1>(a1); a1 = dpp_add<0x4E>(a1); a1 = dpp_add<0x141>(a1);
            a2 = dpp_add<0xB1>(a2); a2 = dpp_add<0x4E>(a2); a2 = dpp_add<0x141>(a2);
            a3 = dpp_add<0xB1>(a3); a3 = dpp_add<0x4E>(a3); a3 = dpp_add<0x141>(a3);

            // (5) lane finalizes gate g = s&3 (pairs redundant)
            const float asum = (g == 0) ? a0 : (g == 1) ? a1 : (g == 2) ? a2 : a3;
            const float gs = asum + xg0;
            const float y  = is_t ? (-2.0f * fabsf(gs)) : (-gs);
            const float r  = fast_rcp(1.0f + __expf(y));
            const float v  = is_t ? copysignf(fmaf(2.0f, r, -1.0f), gs) : r;

            // (6) quad gather (per-quad broadcast), replicated c/h update
            const float fi = dpp_mov<0x00>(v);
            const float ff = dpp_mov<0x55>(v);
            const float tc = dpp_mov<0xAA>(v);
            const float fo = dpp_mov<0xFF>(v);
            c = fmaf(ff, c, fi * tc);
            h = fo * tanh_fast(c);

            const int nxt = cur ^ 1;
            if (act_th && s == 0) s_h[nxt * HS + u] = (_Float16)h;
            hprev = h;
            xg0 = xg1; xg1 = xg2;
        }
        lds_barrier();   // LDS-only: global ops stay in flight
    }

    if (!LAST) {
        if (act_th && s == 0)
            xout[((size_t)b * TC + (TC - 1)) * U + u] = hprev;
    }
    if (act_th && s == 0) {
        c_state[b * U + u] = c;
        h_state[b * U + u] = h;
    }
    if (LAST && tid == 0) {
        float acc = bout[0];
#pragma unroll
        for (int k = 0; k < U; ++k)
            acc = fmaf((float)s_h[cur * HS + k], Wout[k], acc);
        dout[b] = acc;
    }
}

#define REC_ARGS const float* __restrict__ xg, const float* __restrict__ Wh,        \
                 float* __restrict__ xout, float* __restrict__ c_state,             \
                 float* __restrict__ h_state, int first,                            \
                 const float* __restrict__ Wout, const float* __restrict__ bout,    \
                 float* __restrict__ dout
#define REC_PASS xg, Wh, xout, c_state, h_state, first, Wout, bout, dout

__attribute__((amdgpu_flat_work_group_size(832, 832), amdgpu_waves_per_eu(4, 8)))
__global__ void rec_l0(REC_ARGS) {
    __shared__ __align__(16) _Float16 s_h[2 * 8 * 16];
    rec8_body<100, 16, 832, false>(s_h, REC_PASS);
}

__attribute__((amdgpu_flat_work_group_size(640, 640), amdgpu_waves_per_eu(4, 8)))
__global__ void rec_l1(REC_ARGS) {
    __shared__ __align__(16) _Float16 s_h[2 * 8 * 12];
    rec8_body<80, 12, 640, false>(s_h, REC_PASS);
}

__attribute__((amdgpu_flat_work_group_size(448, 448), amdgpu_waves_per_eu(4, 8)))
__global__ void rec_l2(REC_ARGS) {
    __shared__ __align__(16) _Float16 s_h[2 * 8 * 8];
    rec8_body<50, 8, 448, false>(s_h, REC_PASS);
}

__attribute__((amdgpu_flat_work_group_size(256, 256), amdgpu_waves_per_eu(4, 8)))
__global__ void rec_l3(REC_ARGS) {
    __shared__ __align__(16) _Float16 s_h[2 * 8 * 4];
    rec8_body<30, 4, 256, true>(s_h, REC_PASS);
}

extern "C" void kernel_launch(void* const* d_in, const int* in_sizes, int n_in,
                              void* d_out, int out_size, void* d_ws, size_t ws_size,
                              hipStream_t stream)
{
    const float* seq  = (const float*)d_in[0];
    const float* Wx0  = (const float*)d_in[1];
    const float* Wh0  = (const float*)d_in[2];
    const float* b0   = (const float*)d_in[3];
    const float* Wx1  = (const float*)d_in[4];
    const float* Wh1  = (const float*)d_in[5];
    const float* b1   = (const float*)d_in[6];
    const float* Wx2  = (const float*)d_in[7];
    const float* Wh2  = (const float*)d_in[8];
    const float* b2   = (const float*)d_in[9];
    const float* Wx3  = (const float*)d_in[10];
    const float* Wh3  = (const float*)d_in[11];
    const float* b3   = (const float*)d_in[12];
    const float* Wout = (const float*)d_in[13];
    const float* bout = (const float*)d_in[14];
    float* out = (float*)d_out;

    const size_t XG_ELEMS = (size_t)BATCH * TC * 400;
    const size_t XC_ELEMS = (size_t)BATCH * TC * 100;
    float* ws  = (float*)d_ws;
    float* XGa = ws;
    float* XGb = XGa + XG_ELEMS;
    float* Xca = XGb + XG_ELEMS;
    float* Xcb = Xca + XC_ELEMS;
    float* st  = Xcb + XC_ELEMS;
    float* c0 = st + 0 * 32768; float* h0 = st + 1 * 32768;
    float* c1 = st + 2 * 32768; float* h1 = st + 3 * 32768;
    float* c2 = st + 4 * 32768; float* h2 = st + 5 * 32768;
    float* c3 = st + 6 * 32768; float* h3 = st + 7 * 32768;

    const dim3 gB(BATCH);

    for (int j = 0; j < NCHUNK; ++j) {
        const int first = (j == 0) ? 1 : 0;

        xg_gemm<64, 400><<<dim3(7, 512), 256, 0, stream>>>(
            seq + (size_t)j * TC * 64, TFULL * 64, Wx0, b0, XGa);
        rec_l0<<<gB, 832, 0, stream>>>(
            XGa, Wh0, Xca, c0, h0, first, nullptr, nullptr, nullptr);

        xg_gemm<100, 320><<<dim3(5, 512), 256, 0, stream>>>(
            Xca, TC * 100, Wx1, b1, XGb);
        rec_l1<<<gB, 640, 0, stream>>>(
            XGb, Wh1, Xcb, c1, h1, first, nullptr, nullptr, nullptr);

        xg_gemm<80, 200><<<dim3(4, 512), 256, 0, stream>>>(
            Xcb, TC * 80, Wx2, b2, XGa);
        rec_l2<<<gB, 448, 0, stream>>>(
            XGa, Wh2, Xca, c2, h2, first, nullptr, nullptr, nullptr);

        xg_gemm<50, 120><<<dim3(2, 512), 256, 0, stream>>>(
            Xca, TC * 50, Wx3, b3, XGb);
        rec_l3<<<gB, 256, 0, stream>>>(
            XGb, Wh3, nullptr, c3, h3, first, Wout, bout, out);
    }
}

// Round 10
// 3363.666 us; speedup vs baseline: 1.0726x; 1.0726x over previous
//
#include <hip/hip_runtime.h>

// Round 18: R10's proven serial structure (TC=128, per-layer rec kernels,
// 2874us-passing schedule) + R15's proven 4-lane fdot2/f16 rec math.
//  - R10 rec was issue-bound: 306 instr/lane/step, ~160 of them AGPR
//    parking moves for the 112-f32 weight array (VGPR_Count=72).
//  - fdot2 path: weights 56 packed f16x2 regs, dots 112 fma -> 56 fdot2;
//    at waves_per_eu(1,2) (256-reg budget) ~90 regs fit in arch VGPRs.
//  - R15 validated this exact dot/precision path (absmax 2.4e-4); R17's
//    regression was the 8-lane scheme (3rd dpp stage + 13-wave barrier),
//    not fdot2 -- reverted to the 4-lane/7-wave/2-dpp profile.
//  - GEMM side, chunk loop, barriers, prefetch, deferred stores: verbatim
//    from the 2874us baseline.

#define BATCH 256
#define TFULL 1024
#define TC    128
#define NCHUNK (TFULL / TC)

typedef __attribute__((ext_vector_type(2))) _Float16 f16x2;
typedef __attribute__((ext_vector_type(4))) _Float16 f16x4;

__device__ __forceinline__ float fast_rcp(float x) {
    return __builtin_amdgcn_rcpf(x);
}

__device__ __forceinline__ float tanh_fast(float x) {
    float e = __expf(-2.0f * fabsf(x));
    float r = fast_rcp(1.0f + e);
    return copysignf(fmaf(2.0f, r, -1.0f), x);
}

__device__ __forceinline__ float fdot2_(f16x2 a, f16x2 b, float c) {
#if __has_builtin(__builtin_amdgcn_fdot2)
    return __builtin_amdgcn_fdot2(a, b, c, false);
#else
    float d;
    asm("v_dot2_f32_f16 %0, %1, %2, %3" : "=v"(d) : "v"(a), "v"(b), "v"(c));
    return d;
#endif
}

// LDS-only barrier: does NOT drain vmcnt (global loads/stores stay in
// flight). Safe: the rec loop's barrier only orders the LDS h handoff.
__device__ __forceinline__ void lds_barrier() {
    asm volatile("s_waitcnt lgkmcnt(0)\n\ts_barrier" ::: "memory");
}

template<int CTRL>
__device__ __forceinline__ float dpp_add(float v) {
    int t = __builtin_amdgcn_update_dpp(0, __float_as_int(v), CTRL, 0xF, 0xF, true);
    return v + __int_as_float(t);
}
template<int CTRL>
__device__ __forceinline__ float dpp_mov(float v) {
    int t = __builtin_amdgcn_update_dpp(0, __float_as_int(v), CTRL, 0xF, 0xF, true);
    return __int_as_float(t);
}

// ---------------- Phase A: xg = x @ Wx + bias (baseline, verbatim) --------
template<int K, int N>
__global__ __launch_bounds__(256, 2)
void xg_gemm(const float* __restrict__ x, int batchStride,
             const float* __restrict__ Wx,    // [K, N]
             const float* __restrict__ bias,  // [N]
             float* __restrict__ out)
{
    constexpr int K4   = (K + 3) / 4;
    constexpr int SLAB = 64 * 4 + 4;

    const int n0   = blockIdx.x * 64;
    const int row0 = blockIdx.y * 64;
    const int tid  = threadIdx.x;
    const int tx   = tid & 15;
    const int ty   = tid >> 4;

    __shared__ __align__(16) float s_A[K4 * SLAB];
    __shared__ __align__(16) float s_B[K4 * 4 * 64];

    if constexpr ((K % 4) == 0) {
        for (int i = tid; i < 64 * (K / 4); i += 256) {
            const int row = i / (K / 4);
            const int k4  = i % (K / 4);
            const int gr  = row0 + row;
            const int b   = gr >> 7;
            const int t   = gr & 127;
            float4 v = *(const float4*)(x + (size_t)b * batchStride + t * K + k4 * 4);
            *(float4*)(s_A + k4 * SLAB + row * 4) = v;
        }
    } else {
        for (int i = tid; i < 64 * K; i += 256) {
            const int row = i / K;
            const int k   = i % K;
            const int gr  = row0 + row;
            const int b   = gr >> 7;
            const int t   = gr & 127;
            s_A[(k >> 2) * SLAB + row * 4 + (k & 3)] =
                x[(size_t)b * batchStride + t * K + k];
        }
        constexpr int PAD = K4 * 4 - K;
        for (int i = tid; i < 64 * PAD; i += 256) {
            const int row = i / PAD;
            const int kk  = K + i % PAD;
            s_A[(kk >> 2) * SLAB + row * 4 + (kk & 3)] = 0.0f;
        }
    }

    for (int i = tid; i < K4 * 4 * 16; i += 256) {
        const int k  = i >> 4;
        const int c4 = i & 15;
        float4 v = {0.0f, 0.0f, 0.0f, 0.0f};
        if (k < K && n0 + c4 * 4 < N)
            v = *(const float4*)(Wx + (size_t)k * N + n0 + c4 * 4);
        *(float4*)(s_B + k * 64 + c4 * 4) = v;
    }
    __syncthreads();

    float acc[4][4];
#pragma unroll
    for (int r = 0; r < 4; ++r)
#pragma unroll
        for (int c = 0; c < 4; ++c) acc[r][c] = 0.0f;

    for (int k4 = 0; k4 < K4; ++k4) {
        float4 bv[4];
#pragma unroll
        for (int j = 0; j < 4; ++j)
            bv[j] = *(const float4*)(s_B + (k4 * 4 + j) * 64 + tx * 4);
#pragma unroll
        for (int r = 0; r < 4; ++r) {
            float4 av = *(const float4*)(s_A + k4 * SLAB + (ty + 16 * r) * 4);
#pragma unroll
            for (int c = 0; c < 4; ++c) {
                acc[r][c] = fmaf(av.x, ((const float*)&bv[0])[c], acc[r][c]);
                acc[r][c] = fmaf(av.y, ((const float*)&bv[1])[c], acc[r][c]);
                acc[r][c] = fmaf(av.z, ((const float*)&bv[2])[c], acc[r][c]);
                acc[r][c] = fmaf(av.w, ((const float*)&bv[3])[c], acc[r][c]);
            }
        }
    }

    if (n0 + tx * 4 < N) {
        float4 bb = *(const float4*)(bias + n0 + tx * 4);
#pragma unroll
        for (int r = 0; r < 4; ++r) {
            float4 o;
            o.x = acc[r][0] + bb.x;
            o.y = acc[r][1] + bb.y;
            o.z = acc[r][2] + bb.z;
            o.w = acc[r][3] + bb.w;
            *(float4*)(out + (size_t)(row0 + ty + 16 * r) * N + n0 + tx * 4) = o;
        }
    }
}

// ---------------- Phase B: recurrence (4-lane, fdot2 f16 weights) ---------
// 4 lanes per unit (quad-aligned). S: per-lane k-slice (mult of 4, 4*S >= U).
// R10's verified scheme/schedule; h in LDS as f16, weights as packed f16
// pairs, inner product via v_dot2_f32_f16 (f32 accumulate) -- the exact
// precision path R15 measured at absmax 2.4e-4.
template<int U, int S, int BLOCK, bool LAST>
__device__ __forceinline__ void rec4_body(
    _Float16* __restrict__ s_h,     // [2][4*S] f16 in LDS
    const float* __restrict__ xg,   // [B, TC, G]
    const float* __restrict__ Wh,   // [U, G]
    float* __restrict__ xout,       // [B, TC, U] (unless LAST)
    float* __restrict__ c_state,    // [B*U]
    float* __restrict__ h_state,    // [B*U]
    int first,
    const float* __restrict__ Wout, // [U] (LAST)
    const float* __restrict__ bout, // [1] (LAST)
    float* __restrict__ dout)       // [B] (LAST)
{
    constexpr int G  = 4 * U;
    constexpr int HS = 4 * S;

    const int b   = blockIdx.x;
    const int tid = threadIdx.x;
    const int u   = tid >> 2;
    const int s   = tid & 3;
    const bool act_th = (u < U);
    const int uu  = act_th ? u : 0;

    // packed f16 weight pairs: w4[g][kk/2] = (Wh[k0][g*U+u], Wh[k1][g*U+u])
    f16x2 w4[4][S / 2];
#pragma unroll
    for (int g = 0; g < 4; ++g)
#pragma unroll
        for (int kk = 0; kk < S; kk += 2) {
            const int k0 = s * S + kk;
            const int k1 = k0 + 1;
            const float wa = (act_th && k0 < U) ? Wh[(size_t)k0 * G + g * U + uu] : 0.0f;
            const float wb = (act_th && k1 < U) ? Wh[(size_t)k1 * G + g * U + uu] : 0.0f;
            w4[g][kk >> 1] = (f16x2){(_Float16)wa, (_Float16)wb};
        }

    for (int i = tid; i < 2 * HS; i += BLOCK) s_h[i] = (_Float16)0.0f;
    __syncthreads();
    if (tid < U) s_h[tid] = (_Float16)(first ? 0.0f : h_state[b * U + tid]);
    float c = first ? 0.0f : c_state[b * U + uu];
    __syncthreads();

    const float* xgp = xg + (size_t)b * TC * G + (s * U + uu);
    float xg0 = xgp[0];
    float xg1 = xgp[G];

    int cur = 0;
    float h = 0.0f, hprev = 0.0f;
    const bool is_t = (s == 2);

    for (int t = 0; t < TC; ++t, cur ^= 1) {
        // (1) t+2 prefetch: waited at USE two steps from now
        const int tp = (t + 2 < TC) ? (t + 2) : (TC - 1);
        const float xg2 = xgp[(size_t)tp * G];

        // (2) deferred global store of last step's h (never waited at barrier)
        if (!LAST) {
            if (act_th && s == 0 && t > 0)
                xout[((size_t)b * TC + (t - 1)) * U + u] = hprev;
        }

        // (3) partial dots over this lane's k-slice, all 4 gates.
        //     f16 pairs via v_dot2_f32_f16, f32 accumulate.
        float a0 = 0.0f, a1 = 0.0f, a2 = 0.0f, a3 = 0.0f;
        const _Float16* hs = s_h + cur * HS + s * S;
#pragma unroll
        for (int kk = 0; kk < S; kk += 4) {
            f16x4 v = *(const f16x4*)(hs + kk);
            f16x2 lo = __builtin_shufflevector(v, v, 0, 1);
            f16x2 hi = __builtin_shufflevector(v, v, 2, 3);
            const int p = kk >> 1;
            a0 = fdot2_(lo, w4[0][p],     a0);
            a0 = fdot2_(hi, w4[0][p + 1], a0);
            a1 = fdot2_(lo, w4[1][p],     a1);
            a1 = fdot2_(hi, w4[1][p + 1], a1);
            a2 = fdot2_(lo, w4[2][p],     a2);
            a2 = fdot2_(hi, w4[2][p + 1], a2);
            a3 = fdot2_(lo, w4[3][p],     a3);
            a3 = fdot2_(hi, w4[3][p + 1], a3);
        }

        // (4) quad butterfly
        a0 = dpp_add<0xB1>(a0); a0 = dpp_add<0x4E>(a0);
        a1 = dpp_add<0xB1>(a1); a1 = dpp_add<0x4E>(a1);
        a2 = dpp_add<0xB1>(a2); a2 = dpp_add<0x4E>(a2);
        a3 = dpp_add<0xB1>(a3); a3 = dpp_add<0x4E>(a3);

        // (5) lane s finalizes gate s (distributed activation)
        const float asum = (s == 0) ? a0 : (s == 1) ? a1 : (s == 2) ? a2 : a3;
        const float gs = asum + xg0;
        const float y  = is_t ? (-2.0f * fabsf(gs)) : (-gs);
        const float r  = fast_rcp(1.0f + __expf(y));
        const float v  = is_t ? copysignf(fmaf(2.0f, r, -1.0f), gs) : r;

        // (6) gather quad activations, update c/h (replicated)
        const float fi = dpp_mov<0x00>(v);
        const float ff = dpp_mov<0x55>(v);
        const float tc = dpp_mov<0xAA>(v);
        const float fo = dpp_mov<0xFF>(v);
        c = fmaf(ff, c, fi * tc);
        h = fo * tanh_fast(c);

        const int nxt = cur ^ 1;
        if (act_th && s == 0) s_h[nxt * HS + u] = (_Float16)h;
        hprev = h;
        xg0 = xg1; xg1 = xg2;
        lds_barrier();   // LDS-only: global ops stay in flight
    }

    if (!LAST) {
        if (act_th && s == 0)
            xout[((size_t)b * TC + (TC - 1)) * U + u] = hprev;
    }
    if (act_th && s == 0) {
        c_state[b * U + u] = c;
        h_state[b * U + u] = h;
    }
    if (LAST && tid == 0) {
        float acc = bout[0];
#pragma unroll
        for (int k = 0; k < U; ++k)
            acc = fmaf((float)s_h[cur * HS + k], Wout[k], acc);
        dout[b] = acc;
    }
}

#define REC_ARGS const float* __restrict__ xg, const float* __restrict__ Wh,        \
                 float* __restrict__ xout, float* __restrict__ c_state,             \
                 float* __restrict__ h_state, int first,                            \
                 const float* __restrict__ Wout, const float* __restrict__ bout,    \
                 float* __restrict__ dout
#define REC_PASS xg, Wh, xout, c_state, h_state, first, Wout, bout, dout

__attribute__((amdgpu_flat_work_group_size(448, 448), amdgpu_waves_per_eu(1, 2)))
__global__ void rec_l0(REC_ARGS) {
    __shared__ __align__(16) _Float16 s_h[2 * 112];
    rec4_body<100, 28, 448, false>(s_h, REC_PASS);
}

__attribute__((amdgpu_flat_work_group_size(320, 320), amdgpu_waves_per_eu(1, 2)))
__global__ void rec_l1(REC_ARGS) {
    __shared__ __align__(16) _Float16 s_h[2 * 80];
    rec4_body<80, 20, 320, false>(s_h, REC_PASS);
}

__attribute__((amdgpu_flat_work_group_size(256, 256), amdgpu_waves_per_eu(1, 2)))
__global__ void rec_l2(REC_ARGS) {
    __shared__ __align__(16) _Float16 s_h[2 * 64];
    rec4_body<50, 16, 256, false>(s_h, REC_PASS);
}

__attribute__((amdgpu_flat_work_group_size(128, 128), amdgpu_waves_per_eu(1, 2)))
__global__ void rec_l3(REC_ARGS) {
    __shared__ __align__(16) _Float16 s_h[2 * 32];
    rec4_body<30, 8, 128, true>(s_h, REC_PASS);
}

extern "C" void kernel_launch(void* const* d_in, const int* in_sizes, int n_in,
                              void* d_out, int out_size, void* d_ws, size_t ws_size,
                              hipStream_t stream)
{
    const float* seq  = (const float*)d_in[0];
    const float* Wx0  = (const float*)d_in[1];
    const float* Wh0  = (const float*)d_in[2];
    const float* b0   = (const float*)d_in[3];
    const float* Wx1  = (const float*)d_in[4];
    const float* Wh1  = (const float*)d_in[5];
    const float* b1   = (const float*)d_in[6];
    const float* Wx2  = (const float*)d_in[7];
    const float* Wh2  = (const float*)d_in[8];
    const float* b2   = (const float*)d_in[9];
    const float* Wx3  = (const float*)d_in[10];
    const float* Wh3  = (const float*)d_in[11];
    const float* b3   = (const float*)d_in[12];
    const float* Wout = (const float*)d_in[13];
    const float* bout = (const float*)d_in[14];
    float* out = (float*)d_out;

    const size_t XG_ELEMS = (size_t)BATCH * TC * 400;
    const size_t XC_ELEMS = (size_t)BATCH * TC * 100;
    float* ws  = (float*)d_ws;
    float* XGa = ws;
    float* XGb = XGa + XG_ELEMS;
    float* Xca = XGb + XG_ELEMS;
    float* Xcb = Xca + XC_ELEMS;
    float* st  = Xcb + XC_ELEMS;
    float* c0 = st + 0 * 32768; float* h0 = st + 1 * 32768;
    float* c1 = st + 2 * 32768; float* h1 = st + 3 * 32768;
    float* c2 = st + 4 * 32768; float* h2 = st + 5 * 32768;
    float* c3 = st + 6 * 32768; float* h3 = st + 7 * 32768;

    const dim3 gB(BATCH);

    for (int j = 0; j < NCHUNK; ++j) {
        const int first = (j == 0) ? 1 : 0;

        xg_gemm<64, 400><<<dim3(7, 512), 256, 0, stream>>>(
            seq + (size_t)j * TC * 64, TFULL * 64, Wx0, b0, XGa);
        rec_l0<<<gB, 448, 0, stream>>>(
            XGa, Wh0, Xca, c0, h0, first, nullptr, nullptr, nullptr);

        xg_gemm<100, 320><<<dim3(5, 512), 256, 0, stream>>>(
            Xca, TC * 100, Wx1, b1, XGb);
        rec_l1<<<gB, 320, 0, stream>>>(
            XGb, Wh1, Xcb, c1, h1, first, nullptr, nullptr, nullptr);

        xg_gemm<80, 200><<<dim3(4, 512), 256, 0, stream>>>(
            Xcb, TC * 80, Wx2, b2, XGa);
        rec_l2<<<gB, 256, 0, stream>>>(
            XGa, Wh2, Xca, c2, h2, first, nullptr, nullptr, nullptr);

        xg_gemm<50, 120><<<dim3(2, 512), 256, 0, stream>>>(
            Xca, TC * 50, Wx3, b3, XGb);
        rec_l3<<<gB, 128, 0, stream>>>(
            XGb, Wh3, nullptr, c3, h3, first, Wout, bout, out);
    }
}